// Round 10
// baseline (14500.409 us; speedup 1.0000x reference)
//
#include <hip/hip_runtime.h>

// drosophRNN v10: v9 chassis (1024 thr, 16 waves, 2 lgkm barriers/step, DPP
// reductions, pk_fma) with K-amortization to cut LDS wave-instructions AND
// VALU issue at constant wave count:
//  - phase1: 25 groups x 16 lanes (6.25 waves), each lane's 20-float slice
//    feeds K=4 outputs (g, g+25, g+50, g+75) -> LDS read insts halved
//  - AV: K=2 on waves 8-11 (idle in window 1): 25 groups x 8 lanes
//  - wave 7: T0 (w1) + single-wave D7 (w2, v8-verified rank-3 path)
//  - wave 8: output streaming (w1)
// LDS model (R8/R9 lesson): cost ~ per-wave-instruction, not per-byte.

#define SSTEPS 5000
#define PI_D 3.14159265358979323846

typedef float f2 __attribute__((ext_vector_type(2)));

__device__ __forceinline__ f2 pk_fma(f2 a, f2 b, f2 c) {
  f2 d;
  asm("v_pk_fma_f32 %0, %1, %2, %3" : "=v"(d) : "v"(a), "v"(b), "v"(c));
  return d;
}

template<int CTRL, int RM, bool BC>
__device__ __forceinline__ float dpp_mov_f(float x) {
  return __int_as_float(__builtin_amdgcn_update_dpp(0, __float_as_int(x), CTRL, RM, 0xF, BC));
}
__device__ __forceinline__ float scan16(float x) {   // lane15 = sum of its 16-row
  x += dpp_mov_f<0x111,0xF,true>(x);
  x += dpp_mov_f<0x112,0xF,true>(x);
  x += dpp_mov_f<0x114,0xF,true>(x);
  x += dpp_mov_f<0x118,0xF,true>(x);
  return x;
}
__device__ __forceinline__ float scan8(float x) {    // lane7 = sum of its 8-group
  x += dpp_mov_f<0x111,0xF,true>(x);
  x += dpp_mov_f<0x112,0xF,true>(x);
  x += dpp_mov_f<0x114,0xF,true>(x);
  return x;
}
__device__ __forceinline__ float wave_sum(float x) { // all-VALU (DPP) + readlane
  x = scan16(x);
  x += dpp_mov_f<0x142,0xA,false>(x);  // row_bcast15
  x += dpp_mov_f<0x143,0xC,false>(x);  // row_bcast31
  return __int_as_float(__builtin_amdgcn_readlane(__float_as_int(x), 63));
}
// lgkm-only barrier (v9-verified): global stores stay in flight.
__device__ __forceinline__ void bar_lgkm() {
  asm volatile("s_waitcnt lgkmcnt(0)\n\ts_barrier" ::: "memory");
}

__global__ __launch_bounds__(1024, 4) void drosoph_rnn_kernel(
    const float* __restrict__ xin,      // (64,5000,2)
    const float* __restrict__ r0,       // (1,64,300)
    const float* __restrict__ W_HD_HD,  // (100,100)
    const float* __restrict__ W_HD_AVp, // (100,50)
    const float* __restrict__ W_HD_AVm, // (100,50)
    const float* __restrict__ W_AVp_HD, // (50,100)
    const float* __restrict__ W_AVm_HD, // (50,100)  (== W_AVp_HD)
    const float* __restrict__ W_D7_HD,  // factorized analytically
    const float* __restrict__ W_D7_D7,  // rank-1 (0.002)
    const float* __restrict__ W_HD_D7,  // (100,100)
    float* __restrict__ out)            // 64*5000*300 + 64*300
{
  const int b    = blockIdx.x;
  const int t    = threadIdx.x;
  const int lane = t & 63;
  const int wid  = t >> 6;

  // state per parity: [0..99] HD, [100..149] AVp, [150..199] AVm,
  // [200..299] relu(D7), [300..327] zero pad (slice r1=15 reads j in [300,320))
  __shared__ __align__(16) float su[2][328];
  __shared__ float avb[SSTEPS];   // x[:,1] for this batch
  __shared__ float d7r[104];      // raw D7 (current step)

  // ---- roles ----
  const bool p1  = (t < 400);            // phase1: 25 groups x 16 lanes, K=4
  const int  g   = t >> 4;               // group 0..24 -> outputs g+25k
  const int  r1  = t & 15;               // j-slice [20*r1, 20*r1+20)
  const bool w7  = (wid == 7);           // T0 (w1) + D7 (w2)
  const bool pst = (wid == 8);           // streaming (w1)
  const bool pav = (t >= 512) && (t < 712);  // AV (w2): 25 groups x 8, K=2
  const int  ai  = (t - 512) >> 3;       // 0..24 -> outputs ai, ai+25
  const int  qa  = t & 7;

  // ---- phase-1 weights: K=4 outputs, scales folded, packed f2 ----
  f2 w1p[4][10];
  if (p1) {
    #pragma unroll
    for (int k = 0; k < 4; ++k) {
      const int o = g + 25*k;
      #pragma unroll
      for (int q = 0; q < 20; ++q) {
        const int j = 20*r1 + q;
        float w;
        if      (j < 100) w = 10.5f                * W_HD_HD [o*100 + j];
        else if (j < 150) w = 0.70710678118654752f * W_HD_AVp[o*50 + (j-100)];
        else if (j < 200) w = 0.70710678118654752f * W_HD_AVm[o*50 + (j-150)];
        else if (j < 300) w = 0.5f                 * W_HD_D7 [o*100 + (j-200)];
        else w = 0.0f;
        w1p[k][q >> 1][q & 1] = w;
      }
    }
  }

  // ---- AV weights: K=2, chunk-interleaved (qa, qa+8, qa+16, qa+24), packed ----
  f2 wavK[2][8];
  if (pav) {
    #pragma unroll
    for (int m = 0; m < 2; ++m) {
      const int a2 = ai + 25*m;
      #pragma unroll
      for (int u = 0; u < 4; ++u) {
        const int j0 = 4*(qa + 8*u);
        #pragma unroll
        for (int mm = 0; mm < 4; ++mm) {
          const int j = j0 + mm;
          float w = (j < 100) ? W_AVp_HD[a2*100 + j] : 0.0f;
          wavK[m][2*u + (mm >> 1)][mm & 1] = w;
        }
      }
    }
  }

  // ---- D7 trig constants (wave 7; outputs lane and lane+64) ----
  float cw0=0.f, cw1=0.f, sw0=0.f, sw1=0.f, m0w=0.f, m1w=0.f;
  float cdA=0.f, sdA=0.f, cdB=0.f, sdB=0.f;
  if (w7) {
    const int j0 = 2*lane, j1 = 2*lane + 1;
    m0w = (j0 < 100) ? 1.0f : 0.0f;
    m1w = (j1 < 100) ? 1.0f : 0.0f;
    double pj0 = -PI_D + j0*(2.0*PI_D/100.0);
    double pj1 = -PI_D + j1*(2.0*PI_D/100.0);
    cw0 = m0w*(float)cos(pj0);  sw0 = m0w*(float)sin(pj0);
    cw1 = m1w*(float)cos(pj1);  sw1 = m1w*(float)sin(pj1);
    double pA = -PI_D + lane     *(2.0*PI_D/100.0);
    double pB = -PI_D + (lane+64)*(2.0*PI_D/100.0);
    cdA = (float)cos(pA); sdA = (float)sin(pA);
    cdB = (float)cos(pB); sdB = (float)sin(pB);
  }

  // ---- init LDS ----
  if (t < 328) { su[0][t] = 0.f; su[1][t] = 0.f; }
  if (t < 104) d7r[t] = 0.f;
  {
    const float2* x2 = (const float2*)xin + (size_t)b * SSTEPS;
    for (int i = t; i < SSTEPS; i += 1024) avb[i] = x2[i].y;
  }
  if (t < 300) {
    float v = r0[b*300 + t];
    su[0][t] = (t < 200) ? v : fmaxf(v, 0.f);
  }
  __syncthreads();   // prologue only

  float* outb = out + (size_t)b * ((size_t)SSTEPS * 300);
  int p = 0;

  #pragma unroll 1
  for (int s = 0; s < SSTEPS; ++s) {
    const float* suc = su[p];
    float*       sun = su[p^1];
    float T0loc = 0.f;

    // =============== window 1: HD matvec (K=4) / T0 / stream ===============
    if (p1) {
      f2 vv2[10];
      {
        const float4* vp = (const float4*)(suc + 20*r1);
        float4 V0=vp[0], V1=vp[1], V2=vp[2], V3=vp[3], V4=vp[4];
        vv2[0] = f2{V0.x, V0.y}; vv2[1] = f2{V0.z, V0.w};
        vv2[2] = f2{V1.x, V1.y}; vv2[3] = f2{V1.z, V1.w};
        vv2[4] = f2{V2.x, V2.y}; vv2[5] = f2{V2.z, V2.w};
        vv2[6] = f2{V3.x, V3.y}; vv2[7] = f2{V3.z, V3.w};
        vv2[8] = f2{V4.x, V4.y}; vv2[9] = f2{V4.z, V4.w};
      }
      const float hd0 = suc[g],    hd1 = suc[g+25];
      const float hd2 = suc[g+50], hd3 = suc[g+75];
      f2 c0={0.f,0.f}, c1={0.f,0.f}, c2={0.f,0.f}, c3={0.f,0.f};
      #pragma unroll
      for (int q2 = 0; q2 < 10; ++q2) {
        c0 = pk_fma(w1p[0][q2], vv2[q2], c0);
        c1 = pk_fma(w1p[1][q2], vv2[q2], c1);
        c2 = pk_fma(w1p[2][q2], vv2[q2], c2);
        c3 = pk_fma(w1p[3][q2], vv2[q2], c3);
      }
      float e0 = c0[0]+c0[1], e1 = c1[0]+c1[1];
      float e2 = c2[0]+c2[1], e3 = c3[0]+c3[1];
      if (r1 >= 10) { e0 *= hd0; e1 *= hd1; e2 *= hd2; e3 *= hd3; }
      e0 = scan16(e0); e1 = scan16(e1); e2 = scan16(e2); e3 = scan16(e3);
      if (r1 == 15) {
        sun[g]    = fmaf(0.001f, fmaf(-10.25f, hd0, e0), hd0);
        sun[g+25] = fmaf(0.001f, fmaf(-10.25f, hd1, e1), hd1);
        sun[g+50] = fmaf(0.001f, fmaf(-10.25f, hd2, e2), hd2);
        sun[g+75] = fmaf(0.001f, fmaf(-10.25f, hd3, e3), hd3);
      }
    } else if (w7) {
      // T0 = sum relu(D7(s-1)) — step-old data
      float x = 0.f;
      if (lane < 50) { float2 z = *(const float2*)(suc + 200 + 2*lane); x = z.x + z.y; }
      T0loc = wave_sum(x);
    } else if (pst) {
      if (s > 0) {     // stream output row s-1 (fire-and-forget; lgkm barriers)
        float* od = outb + (size_t)(s-1) * 300;
        #pragma unroll
        for (int u = 0; u < 5; ++u) {
          int idx = lane + 64*u;
          if (idx < 300) od[idx] = (idx < 200) ? suc[idx] : d7r[idx-200];
        }
      }
    }
    bar_lgkm();

    // =============== window 2: AV (K=2, waves 8-11) / D7 (wave 7) ===============
    if (pav) {
      const float4* hp = (const float4*)sun;    // hdnew[0..99] + zero pad
      float4 H0 = hp[qa], H1 = hp[qa+8], H2 = hp[qa+16], H3 = hp[qa+24];
      f2 hh2[8];
      hh2[0] = f2{H0.x, H0.y}; hh2[1] = f2{H0.z, H0.w};
      hh2[2] = f2{H1.x, H1.y}; hh2[3] = f2{H1.z, H1.w};
      hh2[4] = f2{H2.x, H2.y}; hh2[5] = f2{H2.z, H2.w};
      hh2[6] = f2{H3.x, H3.y}; hh2[7] = f2{H3.z, H3.w};
      f2 d0 = f2{0.f,0.f}, d1 = f2{0.f,0.f};
      #pragma unroll
      for (int u = 0; u < 8; ++u) {
        d0 = pk_fma(wavK[0][u], hh2[u], d0);
        d1 = pk_fma(wavK[1][u], hh2[u], d1);
      }
      float s0v = scan8(d0[0] + d0[1]);
      float s1v = scan8(d1[0] + d1[1]);
      if (qa == 7) {
        const float gp = avb[s] * 1000.0f;       // av/DT, AV_OFFSET=0
        {
          float oldp = suc[100+ai], oldm = suc[150+ai];
          sun[100+ai] = fmaf(0.1f, fmaf(gp,  s0v, -oldp), oldp);  // DT/TAU_AV=0.1
          sun[150+ai] = fmaf(0.1f, fmaf(-gp, s0v, -oldm), oldm);
        }
        {
          float oldp = suc[125+ai], oldm = suc[175+ai];
          sun[125+ai] = fmaf(0.1f, fmaf(gp,  s1v, -oldp), oldp);
          sun[175+ai] = fmaf(0.1f, fmaf(-gp, s1v, -oldm), oldm);
        }
      }
    } else if (w7) {
      float2 y2 = *(const float2*)(sun + 2*lane);   // hdnew (lane>=50 masked x0)
      float y0 = fmaxf(y2.x, 0.f), y1 = fmaxf(y2.y, 0.f);
      float pS0 = fmaf(m1w, y1, m0w * y0);
      float pC  = fmaf(cw1, y1, cw0 * y0);
      float pS  = fmaf(sw1, y1, sw0 * y0);
      float S0 = wave_sum(pS0);
      float C  = wave_sum(pC);
      float S  = wave_sum(pS);
      float base = fmaf(0.002f, T0loc, 0.01f * S0);
      {
        float d7 = base - 0.01f * fmaf(cdA, C, sdA * S);
        sun[200+lane] = fmaxf(d7, 0.f);
        d7r[lane]     = d7;
      }
      if (lane < 36) {
        float d7 = base - 0.01f * fmaf(cdB, C, sdB * S);
        sun[264+lane] = fmaxf(d7, 0.f);
        d7r[64+lane]  = d7;
      }
    }
    bar_lgkm();
    p ^= 1;
  }

  // ---------- epilogue: output row 4999 + final carry ----------
  if (t < 300) {
    float v = (t < 200) ? su[p][t] : d7r[t-200];
    outb[(size_t)(SSTEPS-1) * 300 + t] = v;
    out[(size_t)64 * SSTEPS * 300 + (size_t)b * 300 + t] = v;
  }
}

extern "C" void kernel_launch(void* const* d_in, const int* in_sizes, int n_in,
                              void* d_out, int out_size, void* d_ws, size_t ws_size,
                              hipStream_t stream) {
  drosoph_rnn_kernel<<<64, 1024, 0, stream>>>(
      (const float*)d_in[0],  // inputs
      (const float*)d_in[1],  // r0
      (const float*)d_in[2],  // W_HD_HD
      (const float*)d_in[3],  // W_HD_AVplus
      (const float*)d_in[4],  // W_HD_AVminus
      (const float*)d_in[5],  // W_AVplus_HD
      (const float*)d_in[6],  // W_AVminus_HD
      (const float*)d_in[7],  // W_Del7_HD
      (const float*)d_in[8],  // W_Del7_Del7
      (const float*)d_in[9],  // W_HD_Del7
      (float*)d_out);
}

// Round 11
// 3910.638 us; speedup vs baseline: 3.7079x; 3.7079x over previous
//
#include <hip/hip_runtime.h>

// drosophRNN v11: v10's K-amortized structure, fixed for the spill that killed it:
//  - 512-thread blocks (8 waves): VGPR budget 256 (amdgpu_waves_per_eu(2)) so the
//    80-VGPR K=4 weight array stays in registers (v10: 1024-thr block -> compiler
//    squeezed to 64 VGPR and spilled to scratch, FETCH +2.5GB).
//  - PERMUTED LDS state layout: HD pos 4g+k = neuron g+25k; AV pos 100+4a+m =
//    {AVp[a],AVm[a],AVp[a+25],AVm[a+25]}. All per-step state reads/writes become
//    b128: hd operands (1 instead of 4xb32), HD write, AV old-read, AV write.
//    Weights are permuted at init to match; streaming un-permutes per-lane.
//  - roles: w1: p1 = t<400 (25 groups x 16 lanes, K=4 outputs), wave7 = T0+stream.
//           w2: pav = t<200 (25 groups x 8 lanes, K=2), wave7 = D7 rank-3.
//  - lgkm-only barriers (v9-verified).
// LDS model (R8/R9): cost ~ per-wave-instruction; est 180 -> ~77 insts/step.

#define SSTEPS 5000
#define PI_D 3.14159265358979323846

typedef float f2 __attribute__((ext_vector_type(2)));

__device__ __forceinline__ f2 pk_fma(f2 a, f2 b, f2 c) {
  f2 d;
  asm("v_pk_fma_f32 %0, %1, %2, %3" : "=v"(d) : "v"(a), "v"(b), "v"(c));
  return d;
}

template<int CTRL, int RM, bool BC>
__device__ __forceinline__ float dpp_mov_f(float x) {
  return __int_as_float(__builtin_amdgcn_update_dpp(0, __float_as_int(x), CTRL, RM, 0xF, BC));
}
__device__ __forceinline__ float scan16(float x) {   // lane15 = sum of its 16-row
  x += dpp_mov_f<0x111,0xF,true>(x);
  x += dpp_mov_f<0x112,0xF,true>(x);
  x += dpp_mov_f<0x114,0xF,true>(x);
  x += dpp_mov_f<0x118,0xF,true>(x);
  return x;
}
__device__ __forceinline__ float scan8(float x) {    // lane7(+8k) = sum of its 8-group
  x += dpp_mov_f<0x111,0xF,true>(x);
  x += dpp_mov_f<0x112,0xF,true>(x);
  x += dpp_mov_f<0x114,0xF,true>(x);
  return x;
}
__device__ __forceinline__ float wave_sum(float x) { // all-VALU (DPP) + readlane
  x = scan16(x);
  x += dpp_mov_f<0x142,0xA,false>(x);  // row_bcast15
  x += dpp_mov_f<0x143,0xC,false>(x);  // row_bcast31
  return __int_as_float(__builtin_amdgcn_readlane(__float_as_int(x), 63));
}
// lgkm-only barrier (v9-verified): global stores stay in flight.
__device__ __forceinline__ void bar_lgkm() {
  asm volatile("s_waitcnt lgkmcnt(0)\n\ts_barrier" ::: "memory");
}

// natural neuron index of permuted LDS position
__device__ __forceinline__ int neuron_of_pos(int pos) {
  if (pos < 100) return (pos >> 2) + 25 * (pos & 3);
  if (pos < 200) {
    int r = pos - 100, a = r >> 2, m = r & 3;
    return 100 + a + (m == 0 ? 0 : (m == 1 ? 50 : (m == 2 ? 25 : 75)));
  }
  return pos;   // D7 region natural; >=300 stays >=300 (zero weight)
}
// permuted LDS position of natural neuron index (n in [0,300))
__device__ __forceinline__ int pos_of_neuron(int n) {
  if (n < 100) return 4 * (n % 25) + n / 25;
  if (n < 200) {
    int uu = n - 100, half = (uu >= 50) ? 1 : 0, w = uu - 50 * half;
    return 100 + 4 * (w % 25) + 2 * (w / 25) + half;
  }
  return n;
}

__global__
__attribute__((amdgpu_flat_work_group_size(512,512)))
__attribute__((amdgpu_waves_per_eu(2)))
void drosoph_rnn_kernel(
    const float* __restrict__ xin,      // (64,5000,2)
    const float* __restrict__ r0,       // (1,64,300)
    const float* __restrict__ W_HD_HD,  // (100,100)
    const float* __restrict__ W_HD_AVp, // (100,50)
    const float* __restrict__ W_HD_AVm, // (100,50)
    const float* __restrict__ W_AVp_HD, // (50,100)  == W_AVm_HD
    const float* __restrict__ W_AVm_HD, // (50,100)
    const float* __restrict__ W_D7_HD,  // factorized analytically
    const float* __restrict__ W_D7_D7,  // rank-1 (0.002)
    const float* __restrict__ W_HD_D7,  // (100,100)
    float* __restrict__ out)            // 64*5000*300 + 64*300
{
  const int b    = blockIdx.x;
  const int t    = threadIdx.x;
  const int lane = t & 63;
  const int wid  = t >> 6;

  // PERMUTED state per parity: [0..99] HD (pos 4g+k = hd[g+25k]),
  // [100..199] AV (pos 100+4a+m), [200..299] relu(D7) natural, [300..327] zero.
  __shared__ __align__(16) float su[2][328];
  __shared__ float avb[SSTEPS];
  __shared__ float d7r[104];           // raw D7 (current step), natural order

  // ---- roles ----
  const bool p1  = (t < 400);          // w1: 25 groups x 16 lanes, K=4
  const int  g   = t >> 4;             // group 0..24 -> outputs g+25k
  const int  r1  = t & 15;             // position slice [20*r1, 20*r1+20)
  const bool pav = (t < 200);          // w2: 25 groups x 8 lanes, K=2 (ai, ai+25)
  const int  ai  = t >> 3;
  const int  qa  = t & 7;
  const bool w7  = (wid == 7);         // w1: T0 + stream; w2: D7

  const float kAV = 0.70710678118654752f;

  // ---- phase-1 weights: K=4 outputs over PERMUTED positions ----
  f2 w1p[4][10];
  if (p1) {
    #pragma unroll
    for (int k = 0; k < 4; ++k) {
      const int o = g + 25*k;
      #pragma unroll
      for (int q = 0; q < 20; ++q) {
        const int pos = 20*r1 + q;
        const int n   = neuron_of_pos(pos);
        float w = 0.0f;
        if      (n < 100) w = 10.5f * W_HD_HD [o*100 + n];
        else if (n < 150) w = kAV   * W_HD_AVp[o*50 + (n-100)];
        else if (n < 200) w = kAV   * W_HD_AVm[o*50 + (n-150)];
        else if (n < 300) w = 0.5f  * W_HD_D7 [o*100 + (n-200)];
        w1p[k][q >> 1][q & 1] = w;
      }
    }
  }

  // ---- AV weights: K=2, chunk-interleaved over PERMUTED positions ----
  f2 wavK[2][8];
  if (pav) {
    #pragma unroll
    for (int m = 0; m < 2; ++m) {
      const int a2 = ai + 25*m;
      #pragma unroll
      for (int u = 0; u < 4; ++u) {
        #pragma unroll
        for (int mm = 0; mm < 4; ++mm) {
          const int pos = 4*(qa + 8*u) + mm;
          float w = 0.0f;
          if (pos < 100) w = W_AVp_HD[a2*100 + neuron_of_pos(pos)];
          wavK[m][2*u + (mm >> 1)][mm & 1] = w;
        }
      }
    }
  }

  // ---- D7 trig constants (wave 7; inputs permuted, outputs natural) ----
  float cw0=0.f, cw1=0.f, sw0=0.f, sw1=0.f, m0w=0.f, m1w=0.f;
  float cdA=0.f, sdA=0.f, cdB=0.f, sdB=0.f;
  if (w7) {
    if (lane < 50) {
      const int n0 = neuron_of_pos(2*lane);
      const int n1 = neuron_of_pos(2*lane + 1);
      m0w = 1.0f; m1w = 1.0f;
      double pj0 = -PI_D + n0*(2.0*PI_D/100.0);
      double pj1 = -PI_D + n1*(2.0*PI_D/100.0);
      cw0 = (float)cos(pj0);  sw0 = (float)sin(pj0);
      cw1 = (float)cos(pj1);  sw1 = (float)sin(pj1);
    }
    double pA = -PI_D + lane     *(2.0*PI_D/100.0);
    double pB = -PI_D + (lane+64)*(2.0*PI_D/100.0);
    cdA = (float)cos(pA); sdA = (float)sin(pA);
    cdB = (float)cos(pB); sdB = (float)sin(pB);
  }

  // ---- init LDS (state written PERMUTED) ----
  if (t < 328) { su[0][t] = 0.f; su[1][t] = 0.f; }
  if (t < 104) d7r[t] = 0.f;
  {
    const float2* x2 = (const float2*)xin + (size_t)b * SSTEPS;
    for (int i = t; i < SSTEPS; i += 512) avb[i] = x2[i].y;
  }
  if (t < 300) {
    float v = r0[b*300 + t];
    if (t >= 200) v = fmaxf(v, 0.f);
    su[0][pos_of_neuron(t)] = v;
  }
  __syncthreads();   // prologue only

  float* outb = out + (size_t)b * ((size_t)SSTEPS * 300);
  int p = 0;

  #pragma unroll 1
  for (int s = 0; s < SSTEPS; ++s) {
    const float* suc = su[p];
    float*       sun = su[p^1];
    float T0loc = 0.f;

    // =============== window 1: HD matvec (K=4) / T0 + stream ===============
    if (p1) {
      f2 vv2[10];
      {
        const float4* vp = (const float4*)(suc + 20*r1);
        float4 V0=vp[0], V1=vp[1], V2=vp[2], V3=vp[3], V4=vp[4];
        vv2[0] = f2{V0.x, V0.y}; vv2[1] = f2{V0.z, V0.w};
        vv2[2] = f2{V1.x, V1.y}; vv2[3] = f2{V1.z, V1.w};
        vv2[4] = f2{V2.x, V2.y}; vv2[5] = f2{V2.z, V2.w};
        vv2[6] = f2{V3.x, V3.y}; vv2[7] = f2{V3.z, V3.w};
        vv2[8] = f2{V4.x, V4.y}; vv2[9] = f2{V4.z, V4.w};
      }
      const float4 hd4 = *(const float4*)(suc + 4*g);   // {hd[g],hd[g+25],hd[g+50],hd[g+75]}
      f2 c0={0.f,0.f}, c1={0.f,0.f}, c2={0.f,0.f}, c3={0.f,0.f};
      #pragma unroll
      for (int q2 = 0; q2 < 10; ++q2) {
        c0 = pk_fma(w1p[0][q2], vv2[q2], c0);
        c1 = pk_fma(w1p[1][q2], vv2[q2], c1);
        c2 = pk_fma(w1p[2][q2], vv2[q2], c2);
        c3 = pk_fma(w1p[3][q2], vv2[q2], c3);
      }
      float e0 = c0[0]+c0[1], e1 = c1[0]+c1[1];
      float e2 = c2[0]+c2[1], e3 = c3[0]+c3[1];
      if (r1 >= 10) { e0 *= hd4.x; e1 *= hd4.y; e2 *= hd4.z; e3 *= hd4.w; }
      e0 = scan16(e0); e1 = scan16(e1); e2 = scan16(e2); e3 = scan16(e3);
      if (r1 == 15) {
        float h0 = fmaf(0.001f, fmaf(-10.25f, hd4.x, e0), hd4.x);
        float h1 = fmaf(0.001f, fmaf(-10.25f, hd4.y, e1), hd4.y);
        float h2 = fmaf(0.001f, fmaf(-10.25f, hd4.z, e2), hd4.z);
        float h3 = fmaf(0.001f, fmaf(-10.25f, hd4.w, e3), hd4.w);
        *(float4*)(sun + 4*g) = make_float4(h0, h1, h2, h3);   // one b128 write
      }
    } else if (w7) {
      // T0 = sum relu(D7(s-1)) — step-old data (natural layout)
      float x = 0.f;
      if (lane < 50) { float2 z = *(const float2*)(suc + 200 + 2*lane); x = z.x + z.y; }
      T0loc = wave_sum(x);
      if (s > 0) {   // stream output row s-1, un-permuting per-lane
        float* od = outb + (size_t)(s-1) * 300;
        #pragma unroll
        for (int u = 0; u < 5; ++u) {
          const int idx = lane + 64*u;
          if (idx < 300) {
            float v;
            if (idx < 100) {
              v = suc[4*(idx % 25) + idx/25];
            } else if (idx < 200) {
              const int uu = idx - 100, half = (uu >= 50) ? 1 : 0;
              const int w_ = uu - 50*half;
              v = suc[100 + 4*(w_ % 25) + 2*(w_/25) + half];
            } else {
              v = d7r[idx - 200];
            }
            od[idx] = v;
          }
        }
      }
    }
    bar_lgkm();

    // =============== window 2: AV (K=2) / D7 ===============
    if (pav) {
      const float4* hp = (const float4*)sun;   // PERMUTED hdnew; pos>=100 x 0-weight
      float4 H0 = hp[qa], H1 = hp[qa+8], H2 = hp[qa+16], H3 = hp[qa+24];
      f2 hh2[8];
      hh2[0] = f2{H0.x, H0.y}; hh2[1] = f2{H0.z, H0.w};
      hh2[2] = f2{H1.x, H1.y}; hh2[3] = f2{H1.z, H1.w};
      hh2[4] = f2{H2.x, H2.y}; hh2[5] = f2{H2.z, H2.w};
      hh2[6] = f2{H3.x, H3.y}; hh2[7] = f2{H3.z, H3.w};
      f2 d0 = f2{0.f,0.f}, d1 = f2{0.f,0.f};
      #pragma unroll
      for (int u = 0; u < 8; ++u) {
        d0 = pk_fma(wavK[0][u], hh2[u], d0);
        d1 = pk_fma(wavK[1][u], hh2[u], d1);
      }
      const float s0v = scan8(d0[0] + d0[1]);
      const float s1v = scan8(d1[0] + d1[1]);
      if (qa == 7) {
        const float gp  = avb[s] * 1000.0f;     // av/DT, AV_OFFSET=0
        const float4 av4 = *(const float4*)(suc + 100 + 4*ai);  // {p0,m0,p1,m1}
        const float np0 = fmaf(0.1f, fmaf(gp,  s0v, -av4.x), av4.x);  // DT/TAU_AV=0.1
        const float nm0 = fmaf(0.1f, fmaf(-gp, s0v, -av4.y), av4.y);
        const float np1 = fmaf(0.1f, fmaf(gp,  s1v, -av4.z), av4.z);
        const float nm1 = fmaf(0.1f, fmaf(-gp, s1v, -av4.w), av4.w);
        *(float4*)(sun + 100 + 4*ai) = make_float4(np0, nm0, np1, nm1);
      }
    } else if (w7) {
      float2 y2 = *(const float2*)(sun + 2*lane);   // permuted hdnew (lane>=50 x0)
      float y0 = fmaxf(y2.x, 0.f), y1 = fmaxf(y2.y, 0.f);
      float pS0 = fmaf(m1w, y1, m0w * y0);
      float pC  = fmaf(cw1, y1, cw0 * y0);
      float pS  = fmaf(sw1, y1, sw0 * y0);
      float S0 = wave_sum(pS0);
      float C  = wave_sum(pC);
      float S  = wave_sum(pS);
      float base = fmaf(0.002f, T0loc, 0.01f * S0);
      {
        float d7 = base - 0.01f * fmaf(cdA, C, sdA * S);
        sun[200+lane] = fmaxf(d7, 0.f);
        d7r[lane]     = d7;
      }
      if (lane < 36) {
        float d7 = base - 0.01f * fmaf(cdB, C, sdB * S);
        sun[264+lane] = fmaxf(d7, 0.f);
        d7r[64+lane]  = d7;
      }
    }
    bar_lgkm();
    p ^= 1;
  }

  // =============== epilogue: row 4999 + final carry (un-permute) ===============
  if (t < 300) {
    float v;
    if (t < 100) {
      v = su[p][4*(t % 25) + t/25];
    } else if (t < 200) {
      const int uu = t - 100, half = (uu >= 50) ? 1 : 0;
      const int w_ = uu - 50*half;
      v = su[p][100 + 4*(w_ % 25) + 2*(w_/25) + half];
    } else {
      v = d7r[t - 200];
    }
    outb[(size_t)(SSTEPS-1) * 300 + t] = v;
    out[(size_t)64 * SSTEPS * 300 + (size_t)b * 300 + t] = v;
  }
}

extern "C" void kernel_launch(void* const* d_in, const int* in_sizes, int n_in,
                              void* d_out, int out_size, void* d_ws, size_t ws_size,
                              hipStream_t stream) {
  drosoph_rnn_kernel<<<64, 512, 0, stream>>>(
      (const float*)d_in[0],  // inputs
      (const float*)d_in[1],  // r0
      (const float*)d_in[2],  // W_HD_HD
      (const float*)d_in[3],  // W_HD_AVplus
      (const float*)d_in[4],  // W_HD_AVminus
      (const float*)d_in[5],  // W_AVplus_HD
      (const float*)d_in[6],  // W_AVminus_HD
      (const float*)d_in[7],  // W_Del7_HD
      (const float*)d_in[8],  // W_Del7_Del7
      (const float*)d_in[9],  // W_HD_Del7
      (float*)d_out);
}